// Round 13
// baseline (25426.689 us; speedup 1.0000x reference)
//
#include <hip/hip_runtime.h>

// LSTM seq2seq: 1000 enc + 1000 dec steps, B=512, H=512, IN=OUT=1.
// ROUND 13: shrink the serial chain further. Wall time = per-group chain
// (groups are independent recurrences; r12 proved co-residency alone doesn't
// cut the chain -- smaller per-block staging did). Grid 1024 = 32 row-groups
// x 32 col-blocks; block (rb,hb): rb=bid>>5 owns rows [rb*16,+16); hb=bid&31
// owns hidden cols [hb*16,+16) -> 64 gate cols (one gate per wave).
// LDS 20.7KB/block (h 16KB + gates[16][68]) -> 4 blocks/CU (83KB LDS,
// launch_bounds(256,4) caps VGPR<=128 -> 16 waves/CU per m69).
// Pointwise: waves 0-1 only (2 cells/thread, 4B h-stores); waves 2-3 idle
// there (no intra-wave divergence).
// Protocol unchanged (proven r6/r12): single-batch global_load_lds aux=17
// (sc0|sc1 LLC-coherent), 4B agent-atomic h stores, flag-broadcast barrier
// (wave0 poll + handoff), fragment-order LDS, m89 C-layout, hi/lo fp16
// weights, HW transcendentals. [absmax 6.1e-5 rounds 5-12]

typedef _Float16 f16x8 __attribute__((ext_vector_type(8)));
typedef _Float16 f16x2 __attribute__((ext_vector_type(2)));
typedef float    f32x4 __attribute__((ext_vector_type(4)));
typedef unsigned int u32;

// 16B global->LDS async copy, sc0|sc1: read at LLC coherence point,
// correct for cross-XCD producers regardless of block placement.
#define GLOAD_LDS16(gp, lp)                                                    \
  __builtin_amdgcn_global_load_lds(                                            \
      (const __attribute__((address_space(1))) void*)(gp),                     \
      (__attribute__((address_space(3))) void*)(lp), 16, 0, 17)

__device__ __forceinline__ void store_h4_llc(_Float16* p, f16x2 v) {
  __hip_atomic_store((u32*)p, __builtin_bit_cast(u32, v),
                     __ATOMIC_RELAXED, __HIP_MEMORY_SCOPE_AGENT);
}

// sigmoid(x) = rcp(1 + e^-x); tanh via e^(-2|x|): both overflow-safe.
__device__ __forceinline__ float sigm(float x) {
  return __builtin_amdgcn_rcpf(1.0f + __expf(-x));
}
__device__ __forceinline__ float tanh_fast(float x) {
  float r = __expf(-2.0f*fabsf(x));
  float t = (1.0f - r)*__builtin_amdgcn_rcpf(1.0f + r);
  return copysignf(t, x);
}

__global__ void init_zero(float* __restrict__ out, int nout,
                          float* __restrict__ wsf, int nws) {
  int i = blockIdx.x*blockDim.x + threadIdx.x;
  int st = gridDim.x*blockDim.x;
  // agent-scope write-through stores: nothing left dirty in any L2
  for (int j=i; j<nout; j+=st)
    __hip_atomic_store(&out[j], 0.f, __ATOMIC_RELAXED, __HIP_MEMORY_SCOPE_AGENT);
  for (int j=i; j<nws;  j+=st)
    __hip_atomic_store(&wsf[j], 0.f, __ATOMIC_RELAXED, __HIP_MEMORY_SCOPE_AGENT);
}

__global__ __launch_bounds__(256, 4) void lstm_main(
    const float* __restrict__ xin,                              // [1000][512]
    const float* __restrict__ encWih, const float* __restrict__ encWhh,
    const float* __restrict__ enc_bih, const float* __restrict__ enc_bhh,
    const float* __restrict__ decWih, const float* __restrict__ decWhh,
    const float* __restrict__ dec_bih, const float* __restrict__ dec_bhh,
    const float* __restrict__ linW, const float* __restrict__ linb,
    float* __restrict__ out,                                    // [1000][512]
    _Float16* __restrict__ hbuf,                                // [2][512][512]
    int* __restrict__ flags)                                    // 1024 x 128B lines
{
  // h tile (16 rows x 512 k) in FRAGMENT order: chunk = ks*64 + lane,
  // lane l: row = l&15, k = ks*32 + (l>>4)*8 -> MFMA A reads lane-linear.
  __shared__ f16x8 h_lds[1024];     // 16 KB
  __shared__ float gates[16][68];   // 4352 B; +4 pad kills stride conflicts

  const int bid = blockIdx.x, tid = threadIdx.x;
  const int rb = bid >> 5, hb = bid & 31;              // rb 0..31, hb 0..31
  const int wid = tid >> 6, lane = tid & 63;           // wave = gate index
  const int lcol = lane & 15, lq = lane >> 4, kq = lq*8;

  // pointwise role (waves 0-1 only): thread owns 2 cells (row, cols u0,u0+1)
  const bool pw = (tid < 128);
  const int b_local = tid >> 3;                        // 0..15 for tid<128
  const int u0 = (tid & 7)*2;
  const int bg = rb*16 + (b_local & 15);
  const int jh0 = hb*16 + u0;

  float linw[2];
  #pragma unroll
  for (int u=0; u<2; ++u) linw[u] = linW[jh0+u];
  const float linbv = linb[0];

  f16x8 wHi[16], wLo[16];           // this wave's gate, 16 k-steps
  float biasv[8], wihv[8];          // [g*2+u]
  float c[2] = {0.f, 0.f};
  int* myflag = flags + bid*32;                        // own 128B line
  const int* pollp = flags + (rb*32 + (lane & 31))*32; // lane's producer line

  // staging source offsets: chunk c=i*256+tid -> fragment-order LDS
  int goff[4];
  #pragma unroll
  for (int i=0; i<4; ++i) {
    const int cch = i*256 + tid;
    const int ks = cch >> 6, l = cch & 63;
    goff[i] = (l & 15)*512 + ks*32 + (l >> 4)*8;
  }

  auto loadW = [&](const float* Whh, const float* bih, const float* bhh,
                   const float* Wih) {
    const int g = wid;                                 // wave = gate
    const float* wr = Whh + (size_t)(g*512 + hb*16 + lcol)*512;
    #pragma unroll
    for (int ks=0; ks<16; ++ks) {
      f16x8 hi, lo;
      #pragma unroll
      for (int i=0; i<8; ++i) {
        float w = wr[ks*32 + kq + i];
        _Float16 hh = (_Float16)w;
        float hf = (float)hh;
        float rem = (w - hf)*2048.0f;
        if (fabsf(hf) < 6.104e-5f) { hh = (_Float16)0.0f; rem = w*2048.0f; }
        hi[i] = hh; lo[i] = (_Float16)rem;
      }
      wHi[ks] = hi; wLo[ks] = lo;
    }
    #pragma unroll
    for (int gg=0; gg<4; ++gg)
      #pragma unroll
      for (int u=0; u<2; ++u) {
        int j = gg*512 + jh0 + u;
        biasv[gg*2+u] = bih[j] + bhh[j];
        wihv[gg*2+u]  = Wih[j];          // IN==1: Wih is [2048][1]
      }
  };

  loadW(encWhh, enc_bih, enc_bhh, encWih);

  for (int s=0; s<2000; ++s) {
    if (s == 1000) loadW(decWhh, dec_bih, dec_bhh, decWih);
    const bool dec = (s >= 1000);
    const int td = s - 1000;
    const _Float16* hr = hbuf + (size_t)((s+1)&1)*(512*512);  // reads h_{s-1}
    _Float16*       hw = hbuf + (size_t)( s   &1)*(512*512);  // writes h_s

    const _Float16* hrb = hr + (size_t)rb*16*512;   // this group's 16-row tile
    f16x8* ldst = &h_lds[(size_t)wid*64];           // wave-uniform base

    // hoist x (pointwise threads): LLC latency hides under staging drain
    float x = 0.0f;
    if (pw) {
      if (!dec) x = xin[(size_t)s*512 + bg];
      else if (td > 0)
        x = __hip_atomic_load(&out[(size_t)(td-1)*512 + bg],
                              __ATOMIC_RELAXED, __HIP_MEMORY_SCOPE_AGENT);
    }

    // ---- stage 16x512 fp16 h tile into LDS: ONE 4-load batch ----
    #pragma unroll
    for (int i=0; i<4; ++i)
      GLOAD_LDS16(hrb + goff[i], ldst + i*256);
    __syncthreads();   // (a) staged block-wide (compiler drains vmcnt)

    // ---- gates = h @ W^T: wave g computes [16 rows x 16 cols] of gate g ----
    f32x4 accH = {0.f,0.f,0.f,0.f}, accL = {0.f,0.f,0.f,0.f};
    #pragma unroll
    for (int ks=0; ks<16; ++ks) {
      const f16x8 a = h_lds[ks*64 + lane];          // ds_read_b128, lane-linear
      accH = __builtin_amdgcn_mfma_f32_16x16x32_f16(a, wHi[ks], accH, 0,0,0);
      accL = __builtin_amdgcn_mfma_f32_16x16x32_f16(a, wLo[ks], accL, 0,0,0);
    }

    // C-layout (m89): col = lane&15, row = (lane>>4)*4 + i
    {
      f32x4 v = accH + accL*(1.0f/2048.0f);
      const int col  = wid*16 + lcol;
      const int row0 = lq*4;
      #pragma unroll
      for (int i=0; i<4; ++i) gates[row0+i][col] = v[i];
    }
    __syncthreads();   // (b)

    // ---- pointwise LSTM cell update (waves 0-1; 2 cells/thread) ----
    if (pw) {
      const float* grow = gates[b_local & 15];
      f16x2 hv2;
      float sp = 0.f;
      #pragma unroll
      for (int u=0; u<2; ++u) {
        float ai = grow[ 0 + u0+u] + biasv[0+u] + x*wihv[0+u];
        float af = grow[16 + u0+u] + biasv[2+u] + x*wihv[2+u];
        float ag = grow[32 + u0+u] + biasv[4+u] + x*wihv[4+u];
        float ao = grow[48 + u0+u] + biasv[6+u] + x*wihv[6+u];
        float iv = sigm(ai);
        float fv = sigm(af);
        float gv = tanh_fast(ag);
        float ov = sigm(ao);
        float cn = fv*c[u] + iv*gv;
        c[u] = cn;
        float hv = ov*tanh_fast(cn);
        hv2[u] = (_Float16)hv;
        sp += hv*linw[u];
      }
      store_h4_llc(hw + (size_t)bg*512 + jh0, hv2);   // 4B write-through to LLC

      if (dec) {  // pred partial: 8-lane reduce (16 cols), one atomic per row
        sp += __shfl_xor(sp, 1);
        sp += __shfl_xor(sp, 2);
        sp += __shfl_xor(sp, 4);
        if ((tid & 7) == 0) {
          float v = sp + (hb == 0 ? linbv : 0.f);
          __hip_atomic_fetch_add(&out[(size_t)td*512 + bg], v,
                                 __ATOMIC_RELAXED, __HIP_MEMORY_SCOPE_AGENT);
        }
      }
    }

    // ---- row-group barrier (r6 form): wave0-only poll + handoff ----
    if (s != 1999) {
      asm volatile("s_waitcnt vmcnt(0)" ::: "memory");  // h stores/atomics acked
      __syncthreads();                                  // (c) block drained
      const int av = s + 1;
      if (tid == 0)
        __hip_atomic_store(myflag, av, __ATOMIC_RELAXED, __HIP_MEMORY_SCOPE_AGENT);
      if (wid == 0) {      // 64 lanes poll 32 producer flags (2 lanes/flag)
        while (!__all(__hip_atomic_load(pollp, __ATOMIC_RELAXED,
                                        __HIP_MEMORY_SCOPE_AGENT) >= av)) { }
      }
      __syncthreads();     // (d) handoff: all waves released by wave0
    }
  }
}

extern "C" void kernel_launch(void* const* d_in, const int* in_sizes, int n_in,
                              void* d_out, int out_size, void* d_ws, size_t ws_size,
                              hipStream_t stream) {
  const float* xin     = (const float*)d_in[0];
  const float* encWih  = (const float*)d_in[1];
  const float* encWhh  = (const float*)d_in[2];
  const float* enc_bih = (const float*)d_in[3];
  const float* enc_bhh = (const float*)d_in[4];
  const float* decWih  = (const float*)d_in[5];
  const float* decWhh  = (const float*)d_in[6];
  const float* dec_bih = (const float*)d_in[7];
  const float* dec_bhh = (const float*)d_in[8];
  const float* linW    = (const float*)d_in[9];
  const float* linb    = (const float*)d_in[10];
  float* out = (float*)d_out;
  char* ws = (char*)d_ws;
  int* flags = (int*)ws;                        // [0, 128KB): 1024 x 128B flag lines
  _Float16* hbuf = (_Float16*)(ws + 131072);    // [128KB, +1MB): h double buffer

  // zero d_out (pred accumulator) + flags + h buffers, every launch
  init_zero<<<512, 256, 0, stream>>>(out, 1000*512, (float*)ws,
                                     (131072 + 2*512*512*2)/4);

  lstm_main<<<dim3(1024), dim3(256), 0, stream>>>(
      xin, encWih, encWhh, enc_bih, enc_bhh,
      decWih, decWhh, dec_bih, dec_bhh,
      linW, linb, out, hbuf, flags);
}

// Round 14
// 13592.162 us; speedup vs baseline: 1.8707x; 1.8707x over previous
//
#include <hip/hip_runtime.h>

// LSTM seq2seq: 1000 enc + 1000 dec steps, B=512, H=512, IN=OUT=1.
// ROUND 14: r12 geometry (proven 12.5ms; r13's 16-row/4-per-CU variant
// exploded FETCH 13x -> reverted) + two protocol chain cuts:
//  (1) PER-WAVE flags: each wave drains its own vmcnt after pointwise and
//      publishes its own flag line (no block-wide sync before publication).
//      Consumers poll 128 lines (32 blocks x 4 waves) with wave0, 2/lane.
//  (2) Decoder feedback via partial slots part[td&1][bg][hb] (plain agent
//      stores, parallel) read+summed next step by the row's 8 threads;
//      d_out atomicAdd moved AFTER the flag (validator-only, hides in poll).
//      Kills the 32-deep same-address RMW tail inside the pre-flag drain.
// Geometry (r12): grid 512 = 16 row-groups x 32 col-blocks; block (rb,hb):
// rows [rb*32,+32), gate cols [hb*16,+16) x4 gates (one gate/wave).
// LDS 41.5KB -> 2 blocks/CU; launch_bounds(256,2).
// Protocol: single-batch global_load_lds aux=17 (sc0|sc1 LLC-coherent),
// 4B agent-atomic h stores, flag-broadcast barrier (wave0 poll + handoff),
// fragment-order LDS, m89 C-layout, hi/lo fp16 weights, HW transcendentals.
// [absmax 6.1e-5 rounds 5-13]

typedef _Float16 f16x8 __attribute__((ext_vector_type(8)));
typedef _Float16 f16x2 __attribute__((ext_vector_type(2)));
typedef float    f32x4 __attribute__((ext_vector_type(4)));
typedef float    f32x2 __attribute__((ext_vector_type(2)));
typedef unsigned long long u64;
typedef unsigned int u32;

#define GLOAD_LDS16(gp, lp)                                                    \
  __builtin_amdgcn_global_load_lds(                                            \
      (const __attribute__((address_space(1))) void*)(gp),                     \
      (__attribute__((address_space(3))) void*)(lp), 16, 0, 17)

__device__ __forceinline__ void store_h4_llc(_Float16* p, f16x2 v) {
  __hip_atomic_store((u32*)p, __builtin_bit_cast(u32, v),
                     __ATOMIC_RELAXED, __HIP_MEMORY_SCOPE_AGENT);
}
__device__ __forceinline__ f32x2 load_f2_llc(const float* p) {
  u64 v = __hip_atomic_load((const u64*)p, __ATOMIC_RELAXED,
                            __HIP_MEMORY_SCOPE_AGENT);
  return __builtin_bit_cast(f32x2, v);
}

// sigmoid(x) = rcp(1 + e^-x); tanh via e^(-2|x|): both overflow-safe.
__device__ __forceinline__ float sigm(float x) {
  return __builtin_amdgcn_rcpf(1.0f + __expf(-x));
}
__device__ __forceinline__ float tanh_fast(float x) {
  float r = __expf(-2.0f*fabsf(x));
  float t = (1.0f - r)*__builtin_amdgcn_rcpf(1.0f + r);
  return copysignf(t, x);
}

__global__ void init_zero(float* __restrict__ out, int nout,
                          float* __restrict__ wsf, int nws) {
  int i = blockIdx.x*blockDim.x + threadIdx.x;
  int st = gridDim.x*blockDim.x;
  for (int j=i; j<nout; j+=st)
    __hip_atomic_store(&out[j], 0.f, __ATOMIC_RELAXED, __HIP_MEMORY_SCOPE_AGENT);
  for (int j=i; j<nws;  j+=st)
    __hip_atomic_store(&wsf[j], 0.f, __ATOMIC_RELAXED, __HIP_MEMORY_SCOPE_AGENT);
}

__global__ __launch_bounds__(256, 2) void lstm_main(
    const float* __restrict__ xin,                              // [1000][512]
    const float* __restrict__ encWih, const float* __restrict__ encWhh,
    const float* __restrict__ enc_bih, const float* __restrict__ enc_bhh,
    const float* __restrict__ decWih, const float* __restrict__ decWhh,
    const float* __restrict__ dec_bih, const float* __restrict__ dec_bhh,
    const float* __restrict__ linW, const float* __restrict__ linb,
    float* __restrict__ out,                                    // [1000][512]
    _Float16* __restrict__ hbuf,                                // [2][512][512]
    int* __restrict__ flags,                                    // 2048 x 128B lines
    float* __restrict__ part)                                   // [2][512][32]
{
  // h tile (32 rows x 512 k) in FRAGMENT order: chunk = (ks*2+half)*64 + lane.
  __shared__ f16x8 h_lds[2048];     // 32 KB
  __shared__ float gates[32][68];   // 8704 B; +4 pad kills stride conflicts

  const int bid = blockIdx.x, tid = threadIdx.x;
  const int rb = bid >> 5, hb = bid & 31;              // rb 0..15, hb 0..31
  const int wid = tid >> 6, lane = tid & 63;           // wave = gate index
  const int lcol = lane & 15, lq = lane >> 4, kq = lq*8;

  // cell-update role: thread owns 2 cells (row b_local, hidden cols u0,u0+1)
  const int b_local = tid >> 3, u0 = (tid & 7)*2;
  const int bg = rb*32 + b_local;
  const int jh0 = hb*16 + u0;

  float linw[2];
  #pragma unroll
  for (int u=0; u<2; ++u) linw[u] = linW[jh0+u];
  const float linbv = linb[0];

  f16x8 wHi[16], wLo[16];           // this wave's gate, 16 k-steps
  float biasv[8], wihv[8];          // [g*2+u]
  float c[2] = {0.f, 0.f};
  int* myflag = flags + (bid*4 + wid)*32;              // own per-WAVE 128B line
  const int* p0 = flags + (rb*128 + lane)*32;          // poll lines (wave0)
  const int* p1 = flags + (rb*128 + 64 + lane)*32;

  // staging source offsets: chunk c=i*256+tid -> fragment-order LDS
  int goff[8];
  #pragma unroll
  for (int i=0; i<8; ++i) {
    const int cch = i*256 + tid;
    const int frag = cch >> 6;                 // 0..31 = ks*2+half
    const int ks = frag >> 1, half = frag & 1;
    const int row_local = half*16 + (cch & 15);
    goff[i] = row_local*512 + ks*32 + ((cch >> 4) & 3)*8;
  }

  auto loadW = [&](const float* Whh, const float* bih, const float* bhh,
                   const float* Wih) {
    const int g = wid;                                 // wave = gate
    const float* wr = Whh + (size_t)(g*512 + hb*16 + lcol)*512;
    #pragma unroll
    for (int ks=0; ks<16; ++ks) {
      f16x8 hi, lo;
      #pragma unroll
      for (int i=0; i<8; ++i) {
        float w = wr[ks*32 + kq + i];
        _Float16 hh = (_Float16)w;
        float hf = (float)hh;
        float rem = (w - hf)*2048.0f;
        if (fabsf(hf) < 6.104e-5f) { hh = (_Float16)0.0f; rem = w*2048.0f; }
        hi[i] = hh; lo[i] = (_Float16)rem;
      }
      wHi[ks] = hi; wLo[ks] = lo;
    }
    #pragma unroll
    for (int gg=0; gg<4; ++gg)
      #pragma unroll
      for (int u=0; u<2; ++u) {
        int j = gg*512 + jh0 + u;
        biasv[gg*2+u] = bih[j] + bhh[j];
        wihv[gg*2+u]  = Wih[j];          // IN==1: Wih is [2048][1]
      }
  };

  loadW(encWhh, enc_bih, enc_bhh, encWih);

  for (int s=0; s<2000; ++s) {
    if (s == 1000) loadW(decWhh, dec_bih, dec_bhh, decWih);
    const bool dec = (s >= 1000);
    const int td = s - 1000;
    const _Float16* hr = hbuf + (size_t)((s+1)&1)*(512*512);  // reads h_{s-1}
    _Float16*       hw = hbuf + (size_t)( s   &1)*(512*512);  // writes h_s

    const _Float16* hrb = hr + (size_t)rb*32*512;   // this group's 32-row tile
    f16x8* ldst = &h_lds[(size_t)wid*64];           // wave-uniform base

    // x for this step: encoder from xin; decoder = sum of 32 partial slots
    // (written by all col-blocks last step, plain parallel stores).
    float x = 0.0f;
    if (!dec) {
      x = xin[(size_t)s*512 + bg];
    } else if (td > 0) {
      const float* pb = part + (size_t)((td-1)&1)*16384 + bg*32 + (tid&7)*4;
      f32x2 a = load_f2_llc(pb);
      f32x2 b2 = load_f2_llc(pb + 2);
      float sm = a[0] + a[1] + b2[0] + b2[1];
      sm += __shfl_xor(sm, 1);
      sm += __shfl_xor(sm, 2);
      sm += __shfl_xor(sm, 4);
      x = sm + linbv;
    }

    // ---- stage 32x512 fp16 h tile into LDS: ONE 8-load batch (max MLP) ----
    #pragma unroll
    for (int i=0; i<8; ++i)
      GLOAD_LDS16(hrb + goff[i], ldst + i*256);
    __syncthreads();   // (a) staged block-wide (compiler drains vmcnt)

    // ---- gates = h @ W^T: wave g computes [32 rows x 16 cols] of gate g ----
    f32x4 accH[2], accL[2];
    accH[0] = {0.f,0.f,0.f,0.f}; accH[1] = {0.f,0.f,0.f,0.f};
    accL[0] = {0.f,0.f,0.f,0.f}; accL[1] = {0.f,0.f,0.f,0.f};

    #pragma unroll
    for (int ks=0; ks<16; ++ks) {
      const f16x8 a0 = h_lds[(ks*2+0)*64 + lane];   // rows 0-15 fragment
      const f16x8 a1 = h_lds[(ks*2+1)*64 + lane];   // rows 16-31 fragment
      accH[0] = __builtin_amdgcn_mfma_f32_16x16x32_f16(a0, wHi[ks], accH[0], 0,0,0);
      accH[1] = __builtin_amdgcn_mfma_f32_16x16x32_f16(a1, wHi[ks], accH[1], 0,0,0);
      accL[0] = __builtin_amdgcn_mfma_f32_16x16x32_f16(a0, wLo[ks], accL[0], 0,0,0);
      accL[1] = __builtin_amdgcn_mfma_f32_16x16x32_f16(a1, wLo[ks], accL[1], 0,0,0);
    }

    // C-layout (m89): col = lane&15, row = (lane>>4)*4 + i
    #pragma unroll
    for (int rt=0; rt<2; ++rt) {
      f32x4 v = accH[rt] + accL[rt]*(1.0f/2048.0f);
      const int col  = wid*16 + lcol;
      const int row0 = rt*16 + lq*4;
      #pragma unroll
      for (int i=0; i<4; ++i) gates[row0+i][col] = v[i];
    }
    __syncthreads();   // (b)

    // ---- pointwise LSTM cell update (2 cells/thread; rows 8/wave) ----
    const float* grow = gates[b_local];
    f16x2 hv2;
    float sp = 0.f;
    #pragma unroll
    for (int u=0; u<2; ++u) {
      float ai = grow[ 0 + u0+u] + biasv[0+u] + x*wihv[0+u];
      float af = grow[16 + u0+u] + biasv[2+u] + x*wihv[2+u];
      float ag = grow[32 + u0+u] + biasv[4+u] + x*wihv[4+u];
      float ao = grow[48 + u0+u] + biasv[6+u] + x*wihv[6+u];
      float iv = sigm(ai);
      float fv = sigm(af);
      float gv = tanh_fast(ag);
      float ov = sigm(ao);
      float cn = fv*c[u] + iv*gv;
      c[u] = cn;
      float hv = ov*tanh_fast(cn);
      hv2[u] = (_Float16)hv;
      sp += hv*linw[u];
    }
    store_h4_llc(hw + (size_t)bg*512 + jh0, hv2);   // 4B write-through to LLC

    // pred partial for this (row, col-block): 8-lane reduce, ONE slot store
    if (dec) {
      sp += __shfl_xor(sp, 1);
      sp += __shfl_xor(sp, 2);
      sp += __shfl_xor(sp, 4);
      if ((tid & 7) == 0)
        __hip_atomic_store(&part[(size_t)(td&1)*16384 + bg*32 + hb], sp,
                           __ATOMIC_RELAXED, __HIP_MEMORY_SCOPE_AGENT);
    }

    // ---- per-wave flag publication (no block-wide pre-sync) ----
    if (s != 1999) {
      asm volatile("s_waitcnt vmcnt(0)" ::: "memory");  // own h+partial acked
      if (lane == 0)
        __hip_atomic_store(myflag, s + 1, __ATOMIC_RELAXED,
                           __HIP_MEMORY_SCOPE_AGENT);
    }

    // d_out accumulation (validator-only): AFTER flag, hides under poll
    if (dec && (tid & 7) == 0) {
      float v = sp + (hb == 0 ? linbv : 0.f);
      __hip_atomic_fetch_add(&out[(size_t)td*512 + bg], v,
                             __ATOMIC_RELAXED, __HIP_MEMORY_SCOPE_AGENT);
    }

    // ---- barrier: wave0 polls 128 per-wave flags, then handoff ----
    if (s != 1999) {
      const int av = s + 1;
      if (wid == 0) {
        while (true) {
          int f0 = __hip_atomic_load(p0, __ATOMIC_RELAXED, __HIP_MEMORY_SCOPE_AGENT);
          int f1 = __hip_atomic_load(p1, __ATOMIC_RELAXED, __HIP_MEMORY_SCOPE_AGENT);
          if (__all((f0 < av ? f0 : f1 < av ? f1 : av) >= av)) break;
        }
      }
      __syncthreads();     // (d) handoff: all waves released by wave0
    } else {
      asm volatile("s_waitcnt vmcnt(0)" ::: "memory");  // final drains
    }
  }
}

extern "C" void kernel_launch(void* const* d_in, const int* in_sizes, int n_in,
                              void* d_out, int out_size, void* d_ws, size_t ws_size,
                              hipStream_t stream) {
  const float* xin     = (const float*)d_in[0];
  const float* encWih  = (const float*)d_in[1];
  const float* encWhh  = (const float*)d_in[2];
  const float* enc_bih = (const float*)d_in[3];
  const float* enc_bhh = (const float*)d_in[4];
  const float* decWih  = (const float*)d_in[5];
  const float* decWhh  = (const float*)d_in[6];
  const float* dec_bih = (const float*)d_in[7];
  const float* dec_bhh = (const float*)d_in[8];
  const float* linW    = (const float*)d_in[9];
  const float* linb    = (const float*)d_in[10];
  float* out = (float*)d_out;
  char* ws = (char*)d_ws;
  int* flags = (int*)ws;                            // [0,256KB): 2048 x 128B lines
  _Float16* hbuf = (_Float16*)(ws + 262144);        // [256KB,+1MB): h dbuf
  float* part = (float*)(ws + 262144 + 1048576);    // [+1.25MB,+128KB): partials

  // zero d_out + flags + h buffers + partials, every launch
  init_zero<<<512, 256, 0, stream>>>(out, 1000*512, (float*)ws,
                                     (262144 + 1048576 + 131072)/4);

  lstm_main<<<dim3(512), dim3(256), 0, stream>>>(
      xin, encWih, encWhh, enc_bih, enc_bhh,
      decWih, decWhh, dec_bih, dec_bhh,
      linW, linb, out, hbuf, flags, part);
}

// Round 15
// 12021.860 us; speedup vs baseline: 2.1150x; 1.1306x over previous
//
#include <hip/hip_runtime.h>

// LSTM seq2seq: 1000 enc + 1000 dec steps, B=512, H=512, IN=OUT=1.
// ROUND 15: r12 verbatim (proven best 12.53ms) + ONE isolated change: the
// decoder feedback convoy fix from r14 (the only good half of that bundle).
//  - pred partials -> private slots part[td&1][bg][hb] (parallel 4B agent
//    stores, drained pre-flag => flag implies visible).
//  - consumers sum the 32 slots themselves (8 thr/row, 2x8B loads + 3
//    shuffles, issued before staging so the RT hides under stage drain).
//  - d_out atomicAdd (validator-only) moved AFTER the flag store: the 32-way
//    same-address RMW convoy serializes during the poll window, not inside
//    the pre-flag drain of every decoder step.
// r14's per-wave flags are REVERTED (4x poll lines, +1.7GB FETCH, +1ms).
// Geometry (r12): grid 512 = 16 row-groups x 32 col-blocks; block (rb,hb):
// rows [rb*32,+32), gate cols [hb*16,+16) x4 gates (one gate/wave).
// LDS 41.5KB -> 2 blocks/CU; launch_bounds(256,2).
// Protocol: single-batch global_load_lds aux=17 (sc0|sc1 LLC-coherent),
// 4B agent-atomic h stores, per-BLOCK flag barrier (wave0 polls 32 lines,
// 2 lanes/flag, + handoff), fragment-order LDS, m89 C-layout, hi/lo fp16
// weights, HW transcendentals. [absmax 6.1e-5 rounds 5-14]

typedef _Float16 f16x8 __attribute__((ext_vector_type(8)));
typedef _Float16 f16x2 __attribute__((ext_vector_type(2)));
typedef float    f32x4 __attribute__((ext_vector_type(4)));
typedef float    f32x2 __attribute__((ext_vector_type(2)));
typedef unsigned long long u64;
typedef unsigned int u32;

#define GLOAD_LDS16(gp, lp)                                                    \
  __builtin_amdgcn_global_load_lds(                                            \
      (const __attribute__((address_space(1))) void*)(gp),                     \
      (__attribute__((address_space(3))) void*)(lp), 16, 0, 17)

__device__ __forceinline__ void store_h4_llc(_Float16* p, f16x2 v) {
  __hip_atomic_store((u32*)p, __builtin_bit_cast(u32, v),
                     __ATOMIC_RELAXED, __HIP_MEMORY_SCOPE_AGENT);
}
__device__ __forceinline__ f32x2 load_f2_llc(const float* p) {
  u64 v = __hip_atomic_load((const u64*)p, __ATOMIC_RELAXED,
                            __HIP_MEMORY_SCOPE_AGENT);
  return __builtin_bit_cast(f32x2, v);
}

// sigmoid(x) = rcp(1 + e^-x); tanh via e^(-2|x|): both overflow-safe.
__device__ __forceinline__ float sigm(float x) {
  return __builtin_amdgcn_rcpf(1.0f + __expf(-x));
}
__device__ __forceinline__ float tanh_fast(float x) {
  float r = __expf(-2.0f*fabsf(x));
  float t = (1.0f - r)*__builtin_amdgcn_rcpf(1.0f + r);
  return copysignf(t, x);
}

__global__ void init_zero(float* __restrict__ out, int nout,
                          float* __restrict__ wsf, int nws) {
  int i = blockIdx.x*blockDim.x + threadIdx.x;
  int st = gridDim.x*blockDim.x;
  for (int j=i; j<nout; j+=st)
    __hip_atomic_store(&out[j], 0.f, __ATOMIC_RELAXED, __HIP_MEMORY_SCOPE_AGENT);
  for (int j=i; j<nws;  j+=st)
    __hip_atomic_store(&wsf[j], 0.f, __ATOMIC_RELAXED, __HIP_MEMORY_SCOPE_AGENT);
}

__global__ __launch_bounds__(256, 2) void lstm_main(
    const float* __restrict__ xin,                              // [1000][512]
    const float* __restrict__ encWih, const float* __restrict__ encWhh,
    const float* __restrict__ enc_bih, const float* __restrict__ enc_bhh,
    const float* __restrict__ decWih, const float* __restrict__ decWhh,
    const float* __restrict__ dec_bih, const float* __restrict__ dec_bhh,
    const float* __restrict__ linW, const float* __restrict__ linb,
    float* __restrict__ out,                                    // [1000][512]
    _Float16* __restrict__ hbuf,                                // [2][512][512]
    int* __restrict__ flags,                                    // 512 x 128B lines
    float* __restrict__ part)                                   // [2][512][32]
{
  // h tile (32 rows x 512 k) in FRAGMENT order: chunk = (ks*2+half)*64 + lane.
  __shared__ f16x8 h_lds[2048];     // 32 KB
  __shared__ float gates[32][68];   // 8704 B; +4 pad kills stride conflicts

  const int bid = blockIdx.x, tid = threadIdx.x;
  const int rb = bid >> 5, hb = bid & 31;              // rb 0..15, hb 0..31
  const int wid = tid >> 6, lane = tid & 63;           // wave = gate index
  const int lcol = lane & 15, lq = lane >> 4, kq = lq*8;

  // cell-update role: thread owns 2 cells (row b_local, hidden cols u0,u0+1)
  const int b_local = tid >> 3, u0 = (tid & 7)*2;
  const int bg = rb*32 + b_local;
  const int jh0 = hb*16 + u0;

  float linw[2];
  #pragma unroll
  for (int u=0; u<2; ++u) linw[u] = linW[jh0+u];
  const float linbv = linb[0];

  f16x8 wHi[16], wLo[16];           // this wave's gate, 16 k-steps
  float biasv[8], wihv[8];          // [g*2+u]
  float c[2] = {0.f, 0.f};
  int* myflag = flags + bid*32;                        // own 128B line
  const int* pollp = flags + (rb*32 + (lane & 31))*32; // lane's producer line

  // staging source offsets: chunk c=i*256+tid -> fragment-order LDS
  int goff[8];
  #pragma unroll
  for (int i=0; i<8; ++i) {
    const int cch = i*256 + tid;
    const int frag = cch >> 6;                 // 0..31 = ks*2+half
    const int ks = frag >> 1, half = frag & 1;
    const int row_local = half*16 + (cch & 15);
    goff[i] = row_local*512 + ks*32 + ((cch >> 4) & 3)*8;
  }

  auto loadW = [&](const float* Whh, const float* bih, const float* bhh,
                   const float* Wih) {
    const int g = wid;                                 // wave = gate
    const float* wr = Whh + (size_t)(g*512 + hb*16 + lcol)*512;
    #pragma unroll
    for (int ks=0; ks<16; ++ks) {
      f16x8 hi, lo;
      #pragma unroll
      for (int i=0; i<8; ++i) {
        float w = wr[ks*32 + kq + i];
        _Float16 hh = (_Float16)w;
        float hf = (float)hh;
        float rem = (w - hf)*2048.0f;
        if (fabsf(hf) < 6.104e-5f) { hh = (_Float16)0.0f; rem = w*2048.0f; }
        hi[i] = hh; lo[i] = (_Float16)rem;
      }
      wHi[ks] = hi; wLo[ks] = lo;
    }
    #pragma unroll
    for (int gg=0; gg<4; ++gg)
      #pragma unroll
      for (int u=0; u<2; ++u) {
        int j = gg*512 + jh0 + u;
        biasv[gg*2+u] = bih[j] + bhh[j];
        wihv[gg*2+u]  = Wih[j];          // IN==1: Wih is [2048][1]
      }
  };

  loadW(encWhh, enc_bih, enc_bhh, encWih);

  for (int s=0; s<2000; ++s) {
    if (s == 1000) loadW(decWhh, dec_bih, dec_bhh, decWih);
    const bool dec = (s >= 1000);
    const int td = s - 1000;
    const _Float16* hr = hbuf + (size_t)((s+1)&1)*(512*512);  // reads h_{s-1}
    _Float16*       hw = hbuf + (size_t)( s   &1)*(512*512);  // writes h_s

    const _Float16* hrb = hr + (size_t)rb*32*512;   // this group's 32-row tile
    f16x8* ldst = &h_lds[(size_t)wid*64];           // wave-uniform base

    // x for this step: encoder from xin; decoder = sum of 32 partial slots
    // (written pre-flag by all col-blocks last step -> visible post-barrier).
    // Issued before staging so the LLC RT hides under the stage drain.
    float x = 0.0f;
    if (!dec) {
      x = xin[(size_t)s*512 + bg];
    } else if (td > 0) {
      const float* pb = part + (size_t)((td-1)&1)*16384 + bg*32 + (tid&7)*4;
      f32x2 a = load_f2_llc(pb);
      f32x2 b2 = load_f2_llc(pb + 2);
      float sm = a[0] + a[1] + b2[0] + b2[1];
      sm += __shfl_xor(sm, 1);
      sm += __shfl_xor(sm, 2);
      sm += __shfl_xor(sm, 4);
      x = sm + linbv;
    }

    // ---- stage 32x512 fp16 h tile into LDS: ONE 8-load batch (max MLP) ----
    #pragma unroll
    for (int i=0; i<8; ++i)
      GLOAD_LDS16(hrb + goff[i], ldst + i*256);
    __syncthreads();   // (a) staged block-wide (compiler drains vmcnt)

    // ---- gates = h @ W^T: wave g computes [32 rows x 16 cols] of gate g ----
    f32x4 accH[2], accL[2];
    accH[0] = {0.f,0.f,0.f,0.f}; accH[1] = {0.f,0.f,0.f,0.f};
    accL[0] = {0.f,0.f,0.f,0.f}; accL[1] = {0.f,0.f,0.f,0.f};

    #pragma unroll
    for (int ks=0; ks<16; ++ks) {
      const f16x8 a0 = h_lds[(ks*2+0)*64 + lane];   // rows 0-15 fragment
      const f16x8 a1 = h_lds[(ks*2+1)*64 + lane];   // rows 16-31 fragment
      accH[0] = __builtin_amdgcn_mfma_f32_16x16x32_f16(a0, wHi[ks], accH[0], 0,0,0);
      accH[1] = __builtin_amdgcn_mfma_f32_16x16x32_f16(a1, wHi[ks], accH[1], 0,0,0);
      accL[0] = __builtin_amdgcn_mfma_f32_16x16x32_f16(a0, wLo[ks], accL[0], 0,0,0);
      accL[1] = __builtin_amdgcn_mfma_f32_16x16x32_f16(a1, wLo[ks], accL[1], 0,0,0);
    }

    // C-layout (m89): col = lane&15, row = (lane>>4)*4 + i
    #pragma unroll
    for (int rt=0; rt<2; ++rt) {
      f32x4 v = accH[rt] + accL[rt]*(1.0f/2048.0f);
      const int col  = wid*16 + lcol;
      const int row0 = rt*16 + lq*4;
      #pragma unroll
      for (int i=0; i<4; ++i) gates[row0+i][col] = v[i];
    }
    __syncthreads();   // (b)

    // ---- pointwise LSTM cell update (2 cells/thread) ----
    const float* grow = gates[b_local];
    f16x2 hv2;
    float sp = 0.f;
    #pragma unroll
    for (int u=0; u<2; ++u) {
      float ai = grow[ 0 + u0+u] + biasv[0+u] + x*wihv[0+u];
      float af = grow[16 + u0+u] + biasv[2+u] + x*wihv[2+u];
      float ag = grow[32 + u0+u] + biasv[4+u] + x*wihv[4+u];
      float ao = grow[48 + u0+u] + biasv[6+u] + x*wihv[6+u];
      float iv = sigm(ai);
      float fv = sigm(af);
      float gv = tanh_fast(ag);
      float ov = sigm(ao);
      float cn = fv*c[u] + iv*gv;
      c[u] = cn;
      float hv = ov*tanh_fast(cn);
      hv2[u] = (_Float16)hv;
      sp += hv*linw[u];
    }
    store_h4_llc(hw + (size_t)bg*512 + jh0, hv2);   // 4B write-through to LLC

    // pred partial for this (row, col-block): 8-lane reduce, ONE slot store
    // (pre-flag: drained by sync(c)'s vmcnt, so flag implies visible)
    if (dec) {
      sp += __shfl_xor(sp, 1);
      sp += __shfl_xor(sp, 2);
      sp += __shfl_xor(sp, 4);
      if ((tid & 7) == 0)
        __hip_atomic_store(&part[(size_t)(td&1)*16384 + bg*32 + hb], sp,
                           __ATOMIC_RELAXED, __HIP_MEMORY_SCOPE_AGENT);
    }

    // ---- row-group barrier (r12 form): drain, sync, flag, wave0 poll ----
    if (s != 1999) {
      asm volatile("s_waitcnt vmcnt(0)" ::: "memory");  // h + partial acked
      __syncthreads();                                  // (c) block drained
      const int av = s + 1;
      if (tid == 0)
        __hip_atomic_store(myflag, av, __ATOMIC_RELAXED, __HIP_MEMORY_SCOPE_AGENT);

      // d_out accumulation (validator-only): AFTER flag -> convoy hides in poll
      if (dec && (tid & 7) == 0) {
        float v = sp + (hb == 0 ? linbv : 0.f);
        __hip_atomic_fetch_add(&out[(size_t)td*512 + bg], v,
                               __ATOMIC_RELAXED, __HIP_MEMORY_SCOPE_AGENT);
      }

      if (wid == 0) {      // 64 lanes poll 32 producer flags (2 lanes/flag)
        while (!__all(__hip_atomic_load(pollp, __ATOMIC_RELAXED,
                                        __HIP_MEMORY_SCOPE_AGENT) >= av)) { }
      }
      __syncthreads();     // (d) handoff: all waves released by wave0
    } else {
      // final step: d_out add still required; kernel-end drains it
      if (dec && (tid & 7) == 0) {
        float v = sp + (hb == 0 ? linbv : 0.f);
        __hip_atomic_fetch_add(&out[(size_t)td*512 + bg], v,
                               __ATOMIC_RELAXED, __HIP_MEMORY_SCOPE_AGENT);
      }
    }
  }
}

extern "C" void kernel_launch(void* const* d_in, const int* in_sizes, int n_in,
                              void* d_out, int out_size, void* d_ws, size_t ws_size,
                              hipStream_t stream) {
  const float* xin     = (const float*)d_in[0];
  const float* encWih  = (const float*)d_in[1];
  const float* encWhh  = (const float*)d_in[2];
  const float* enc_bih = (const float*)d_in[3];
  const float* enc_bhh = (const float*)d_in[4];
  const float* decWih  = (const float*)d_in[5];
  const float* decWhh  = (const float*)d_in[6];
  const float* dec_bih = (const float*)d_in[7];
  const float* dec_bhh = (const float*)d_in[8];
  const float* linW    = (const float*)d_in[9];
  const float* linb    = (const float*)d_in[10];
  float* out = (float*)d_out;
  char* ws = (char*)d_ws;
  int* flags = (int*)ws;                            // [0,64KB): 512 x 128B lines
  _Float16* hbuf = (_Float16*)(ws + 65536);         // [64KB,+1MB): h dbuf
  float* part = (float*)(ws + 65536 + 1048576);     // [+1MB,+128KB): partials

  // zero d_out + flags + h buffers + partials, every launch
  init_zero<<<512, 256, 0, stream>>>(out, 1000*512, (float*)ws,
                                     (65536 + 1048576 + 131072)/4);

  lstm_main<<<dim3(512), dim3(256), 0, stream>>>(
      xin, encWih, encWhh, enc_bih, enc_bhh,
      decWih, decWhh, dec_bih, dec_bhh,
      linW, linb, out, hbuf, flags, part);
}